// Round 9
// baseline (508.468 us; speedup 1.0000x reference)
//
#include <hip/hip_runtime.h>
#include <math.h>

#define NA 16384
#define NE 262144

// workspace layout in floats
#define SI_OFF   0                         // [NA][3]
#define SB_OFF   (NA*3)                    // [NA][3][96]  atom-major
#define NM_OFF   (SB_OFF + 3*NA*96)        // [NA][13][32] component-major
#define RWT_OFF  (NM_OFF + NA*416)         // [3][96][8]  rbf_w transposed
#define WS_FLOATS (RWT_OFF + 3*96*8)
// int region (reuse ws, cast to int*)
#define HIST_OFF (WS_FLOATS)               // [NA] ints
#define PERM_OFF (HIST_OFF + NA)           // [NE] ints

__global__ __launch_bounds__(256) void repack_rw_k(const float* __restrict__ rbf_w,
                                                   float* __restrict__ ws) {
    int t = blockIdx.x * 256 + threadIdx.x;       // over 3*96*8 = 2304
    if (t >= 2304) return;
    int k = t & 7;
    int c = (t >> 3) % 96;
    int w = t / 768;
    ws[RWT_OFF + t] = rbf_w[w * 768 + k * 96 + c];
}

__global__ __launch_bounds__(256) void hist_zero_k(int* __restrict__ hist) {
    int t = blockIdx.x * 256 + threadIdx.x;
    if (t < NA) hist[t] = 0;
}

__global__ __launch_bounds__(256) void hist_k(const int* __restrict__ idx_j,
                                              int* __restrict__ hist) {
    int e = blockIdx.x * 256 + threadIdx.x;
    if (e < NE) atomicAdd(&hist[idx_j[e]], 1);
}

// single block, 256 threads, 64 entries each: counts -> exclusive offsets
__global__ __launch_bounds__(256) void scan_k(int* __restrict__ hist) {
    __shared__ int sums[256];
    int t = threadIdx.x;
    int lo = t * 64;
    int s = 0;
    for (int k = 0; k < 64; ++k) s += hist[lo + k];
    sums[t] = s;
    __syncthreads();
    for (int off = 1; off < 256; off <<= 1) {
        int v = (t >= off) ? sums[t - off] : 0;
        __syncthreads();
        sums[t] += v;
        __syncthreads();
    }
    int ex = sums[t] - s;                 // exclusive prefix of this chunk
    for (int k = 0; k < 64; ++k) {
        int c = hist[lo + k];
        hist[lo + k] = ex;
        ex += c;
    }
}

__global__ __launch_bounds__(256) void scatter_k(const int* __restrict__ idx_j,
                                                 int* __restrict__ hist,
                                                 int* __restrict__ perm) {
    int e = blockIdx.x * 256 + threadIdx.x;
    if (e < NE) {
        int pos = atomicAdd(&hist[idx_j[e]], 1);
        perm[pos] = e;
    }
}

__global__ __launch_bounds__(256) void atom_prep_k(
    const float* __restrict__ node0, const float* __restrict__ node1,
    const float* __restrict__ node2, const float* __restrict__ spin,
    const float* __restrict__ srbf_w, const float* __restrict__ srbf_b,
    const float* __restrict__ U_w, float* __restrict__ ws)
{
    const int wave = threadIdx.x >> 6;
    const int lane = threadIdx.x & 63;
    const int a = blockIdx.x * 4 + wave;
    if (a >= NA) return;

    float sx = spin[a*3+0], sy = spin[a*3+1], sz = spin[a*3+2];
    float mi = sqrtf(sx*sx + sy*sy + sz*sz + 1e-12f);
    float inv = 1.0f / mi;
    if (lane < 3) ws[SI_OFF + a*3 + lane] = spin[a*3 + lane] * inv;

    float srbf[8];
    #pragma unroll
    for (int k = 0; k < 8; ++k) {
        float d = mi - (float)k * (3.0f / 7.0f);
        srbf[k] = expf(-4.0f * d * d);
    }

    // sb atom-major: [a][w][c] -> one contiguous 1152B region per atom
    #pragma unroll
    for (int w = 0; w < 3; ++w) {
        #pragma unroll
        for (int rep = 0; rep < 2; ++rep) {
            int c = rep * 64 + lane;
            if (c < 96) {
                float acc = srbf_b[w*96 + c];
                #pragma unroll
                for (int k = 0; k < 8; ++k)
                    acc = fmaf(srbf[k], srbf_w[w*768 + k*96 + c], acc);
                ws[SB_OFF + (size_t)a*288 + w*96 + c] = acc;
            }
        }
    }

    const int o = lane & 31;
    const int h = lane >> 5;
    float acc[13];
    #pragma unroll
    for (int sp = 0; sp < 13; ++sp) acc[sp] = 0.0f;

    for (int cc = 0; cc < 16; ++cc) {
        int c = h * 16 + cc;
        float f0 = node0[a*32 + c];
        float u0 = U_w[0*1024 + c*32 + o];
        float u1 = U_w[1*1024 + c*32 + o];
        float u2 = U_w[2*1024 + c*32 + o];
        acc[0] = fmaf(f0, u0, acc[0]);
        #pragma unroll
        for (int jj = 0; jj < 3; ++jj)
            acc[1+jj] = fmaf(node1[a*96 + c*3 + jj], u1, acc[1+jj]);
        #pragma unroll
        for (int ij = 0; ij < 9; ++ij)
            acc[4+ij] = fmaf(node2[a*288 + c*9 + ij], u2, acc[4+ij]);
    }
    #pragma unroll
    for (int sp = 0; sp < 13; ++sp)
        acc[sp] += __shfl_xor(acc[sp], 32);

    // nm component-major: [a][sp][o] -> 13 x 128B rows, each written
    // coalesced by the 32 lanes of the h==0 half-wave
    if (h == 0) {
        float* p = ws + NM_OFF + (size_t)a*416;
        #pragma unroll
        for (int sp = 0; sp < 13; ++sp)
            p[sp*32 + o] = acc[sp];
    }
}

// Phase A: per-edge s[3][32] + u, j-sorted (perm) order, w-sequential.
// sb is atom-major: the random-i fetch is ONE contiguous 1152B region
// (ways 1-2 hit L1 after way 0 touches it) instead of 3 random streams.
__global__ __launch_bounds__(256) void edge_s_k(
    const float* __restrict__ coord, const int* __restrict__ idx_i,
    const int* __restrict__ idx_j, const float* __restrict__ rbf_b,
    const float* __restrict__ V_w, const float* __restrict__ ws,
    const int* __restrict__ perm, float* __restrict__ out)
{
    const int t = blockIdx.x * 256 + threadIdx.x;
    const int e = perm[t];                 // edges sorted by idx_j for locality
    const int i = idx_i[e];
    const int j = idx_j[e];

    float rx = coord[j*3+0] - coord[i*3+0];
    float ry = coord[j*3+1] - coord[i*3+1];
    float rz = coord[j*3+2] - coord[i*3+2];
    float d2 = rx*rx + ry*ry + rz*rz + 1e-12f;
    float dij = sqrtf(d2);
    float invd = 1.0f / dij;
    float ux = rx*invd, uy = ry*invd, uz = rz*invd;

    float tt = fminf(dij * 0.2f, 1.0f);
    float fc = 0.5f * (cosf(3.14159265358979323846f * tt) + 1.0f);
    float rbf[8];
    #pragma unroll
    for (int k = 0; k < 8; ++k) {
        float d = dij - (float)k * (5.0f / 7.0f);
        rbf[k] = expf(-4.0f * d * d) * fc;
    }

    const float* si = ws + SI_OFF;
    float sij = si[i*3+0]*si[j*3+0] + si[i*3+1]*si[j*3+1] + si[i*3+2]*si[j*3+2];
    float cheb1 = sij;
    float cheb2 = 2.0f * sij * sij - 1.0f;

    float* o2 = out + (size_t)NE*128 + (size_t)e*288;
    const float* sbi_a = ws + SB_OFF + (size_t)i*288;
    const float* sbj_a = ws + SB_OFF + (size_t)j*288;

    #pragma unroll 1
    for (int w = 0; w < 3; ++w) {
        const float* sbi = sbi_a + w*96;
        const float* sbj = sbj_a + w*96;
        const float* rwt = ws + RWT_OFF + w*768;   // [96][8]
        const float* rbb = rbf_b + w*96;
        const float* vw  = V_w + w*3072;           // [96][32]

        float s[32];
        #pragma unroll
        for (int o = 0; o < 32; ++o) s[o] = 0.0f;

        #pragma unroll
        for (int tb = 0; tb < 3; ++tb) {
            float chb = (tb == 0) ? 1.0f : ((tb == 1) ? cheb1 : cheb2);
            #pragma unroll 4
            for (int cc = 0; cc < 8; ++cc) {
                int c0 = tb*32 + cc*4;
                float4 vi = *(const float4*)(sbi + c0);
                float4 vj = *(const float4*)(sbj + c0);
                float pv[4];
                pv[0] = vi.x * vj.x; pv[1] = vi.y * vj.y;
                pv[2] = vi.z * vj.z; pv[3] = vi.w * vj.w;
                #pragma unroll
                for (int q = 0; q < 4; ++q) {
                    int c = c0 + q;
                    float rm = rbb[c];
                    #pragma unroll
                    for (int k = 0; k < 8; ++k)
                        rm = fmaf(rbf[k], rwt[c*8 + k], rm);
                    float g = rm * pv[q] * chb;
                    const float* vc = vw + c*32;
                    #pragma unroll
                    for (int o = 0; o < 32; ++o)
                        s[o] = fmaf(vc[o], g, s[o]);
                }
            }
        }

        // one full 128B line per way
        #pragma unroll
        for (int og = 0; og < 8; ++og)
            *(float4*)(o2 + w*32 + og*4) =
                make_float4(s[og*4+0], s[og*4+1], s[og*4+2], s[og*4+3]);
    }

    // 4th line: u vector + zero padding (full 128B line, no RFO)
    *(float4*)(o2 + 96)  = make_float4(ux, uy, uz, 0.0f);
    #pragma unroll
    for (int k = 1; k < 8; ++k)
        *(float4*)(o2 + 96 + k*4) = make_float4(0.f, 0.f, 0.f, 0.f);
}

__device__ __forceinline__ float get4(const float4& v, int oo) {
    switch (oo) {
        case 0:  return v.x;
        case 1:  return v.y;
        case 2:  return v.z;
        default: return v.w;
    }
}

__device__ __forceinline__ void edge_epilogue(
    int e, int q,
    float4 v0, float4 v1, float4 v2, float4 uu,
    const float4* cm, float* __restrict__ out)
{
    float ux = uu.x, uy = uu.y, uz = uu.z;
    float c0[4] = {v0.x, v0.y, v0.z, v0.w};
    float c1[4] = {v1.x, v1.y, v1.z, v1.w};
    float c2[4] = {v2.x, v2.y, v2.z, v2.w};

    float r0[4], r1[12], r2[36];
    #pragma unroll
    for (int oo = 0; oo < 4; ++oo) {
        float n0  = get4(cm[0], oo);
        float n1x = get4(cm[1], oo), n1y = get4(cm[2], oo), n1z = get4(cm[3], oo);
        float t00 = get4(cm[4], oo), t01 = get4(cm[5], oo), t02 = get4(cm[6], oo);
        float t10 = get4(cm[7], oo), t11 = get4(cm[8], oo), t12 = get4(cm[9], oo);
        float t20 = get4(cm[10], oo), t21 = get4(cm[11], oo), t22 = get4(cm[12], oo);
        float s0 = c0[oo], s1 = c1[oo], s2 = c2[oo];

        float d1 = n1x*ux + n1y*uy + n1z*uz;
        float m0 = t00*ux + t01*uy + t02*uz;
        float m1 = t10*ux + t11*uy + t12*uz;
        float m2 = t20*ux + t21*uy + t22*uz;
        float qq = m0*ux + m1*uy + m2*uz;

        r0[oo] = n0*s0 + d1*s1 + qq*s2;

        float w1 = n0*s1 + s2*d1;
        r1[oo*3+0] = w1*ux + n1x*s0 + s1*m0;
        r1[oo*3+1] = w1*uy + n1y*s0 + s1*m1;
        r1[oo*3+2] = w1*uz + n1z*s0 + s1*m2;

        float n0s2 = n0*s2;
        float a0 = ux*n0s2 + s1*n1x + s2*m0;
        float a1 = uy*n0s2 + s1*n1y + s2*m1;
        float a2 = uz*n0s2 + s1*n1z + s2*m2;
        r2[oo*9+0] = a0*ux + s0*t00;
        r2[oo*9+1] = a0*uy + s0*t01;
        r2[oo*9+2] = a0*uz + s0*t02;
        r2[oo*9+3] = a1*ux + s0*t10;
        r2[oo*9+4] = a1*uy + s0*t11;
        r2[oo*9+5] = a1*uz + s0*t12;
        r2[oo*9+6] = a2*ux + s0*t20;
        r2[oo*9+7] = a2*uy + s0*t21;
        r2[oo*9+8] = a2*uz + s0*t22;
    }

    *(float4*)(out + (size_t)e*32 + q*4) =
        make_float4(r0[0], r0[1], r0[2], r0[3]);

    float* p1 = out + (size_t)NE*32 + (size_t)e*96 + q*12;
    #pragma unroll
    for (int k = 0; k < 3; ++k)
        *(float4*)(p1 + k*4) =
            make_float4(r1[k*4+0], r1[k*4+1], r1[k*4+2], r1[k*4+3]);

    float* p2 = out + (size_t)NE*128 + (size_t)e*288 + q*36;
    #pragma unroll
    for (int k = 0; k < 9; ++k)
        *(float4*)(p2 + k*4) =
            make_float4(r2[k*4+0], r2[k*4+1], r2[k*4+2], r2[k*4+3]);
}

// Phase B: NATURAL order (dense writes), 8 threads/edge, 2-deep pinned
// pipeline (r8 win). nm is component-major: 13 float4 loads/thread/edge,
// each 128B row consumed coalesced by the group's 8 lanes (was 16 ops over
// strided [32][16] rows).
__global__ __launch_bounds__(256, 2) void edge_out_k(
    const int* __restrict__ idx_j, const float* __restrict__ ws,
    float* __restrict__ out)
{
    const int t = blockIdx.x * 256 + threadIdx.x;  // (NE/2)*8 threads
    const int g = t >> 3;
    const int q = t & 7;
    const int ea = g;
    const int eb = g + NE/2;
    const int ja = idx_j[ea];
    const int jb = idx_j[eb];

    const float* o2a = out + (size_t)NE*128 + (size_t)ea*288;
    const float* o2b = out + (size_t)NE*128 + (size_t)eb*288;
    const float* nma = ws + NM_OFF + (size_t)ja*416;
    const float* nmb = ws + NM_OFF + (size_t)jb*416;

    // ---- issue ALL loads for BOTH edges ----
    float4 a_v0 = *(const float4*)(o2a + q*4);
    float4 a_v1 = *(const float4*)(o2a + 32 + q*4);
    float4 a_v2 = *(const float4*)(o2a + 64 + q*4);
    float4 a_uu = *(const float4*)(o2a + 96);
    float4 a_cm[13];
    #pragma unroll
    for (int k = 0; k < 13; ++k)
        a_cm[k] = *(const float4*)(nma + k*32 + q*4);

    float4 b_v0 = *(const float4*)(o2b + q*4);
    float4 b_v1 = *(const float4*)(o2b + 32 + q*4);
    float4 b_v2 = *(const float4*)(o2b + 64 + q*4);
    float4 b_uu = *(const float4*)(o2b + 96);
    float4 b_cm[13];
    #pragma unroll
    for (int k = 0; k < 13; ++k)
        b_cm[k] = *(const float4*)(nmb + k*32 + q*4);

    // pin the schedule: all 34 gathers stay in flight together
    __builtin_amdgcn_sched_barrier(0);

    edge_epilogue(ea, q, a_v0, a_v1, a_v2, a_uu, a_cm, out);
    edge_epilogue(eb, q, b_v0, b_v1, b_v2, b_uu, b_cm, out);
}

extern "C" void kernel_launch(void* const* d_in, const int* in_sizes, int n_in,
                              void* d_out, int out_size, void* d_ws, size_t ws_size,
                              hipStream_t stream) {
    const float* node0  = (const float*)d_in[0];
    const float* node1  = (const float*)d_in[1];
    const float* node2  = (const float*)d_in[2];
    const float* coord  = (const float*)d_in[3];
    const float* spin   = (const float*)d_in[4];
    const int*   idx_i  = (const int*)d_in[5];
    const int*   idx_j  = (const int*)d_in[6];
    const float* rbf_w  = (const float*)d_in[7];
    const float* rbf_b  = (const float*)d_in[8];
    const float* srbf_w = (const float*)d_in[9];
    const float* srbf_b = (const float*)d_in[10];
    const float* U_w    = (const float*)d_in[11];
    const float* V_w    = (const float*)d_in[12];
    float* out = (float*)d_out;
    float* ws  = (float*)d_ws;
    int*   wsi = (int*)d_ws;
    int*   hist = wsi + HIST_OFF;
    int*   perm = wsi + PERM_OFF;

    repack_rw_k<<<(2304 + 255) / 256, 256, 0, stream>>>(rbf_w, ws);
    atom_prep_k<<<NA / 4, 256, 0, stream>>>(node0, node1, node2, spin,
                                            srbf_w, srbf_b, U_w, ws);
    hist_zero_k<<<NA / 256, 256, 0, stream>>>(hist);
    hist_k<<<NE / 256, 256, 0, stream>>>(idx_j, hist);
    scan_k<<<1, 256, 0, stream>>>(hist);
    scatter_k<<<NE / 256, 256, 0, stream>>>(idx_j, hist, perm);
    edge_s_k<<<NE / 256, 256, 0, stream>>>(coord, idx_i, idx_j, rbf_b,
                                           V_w, ws, perm, out);
    edge_out_k<<<(NE / 2 * 8) / 256, 256, 0, stream>>>(idx_j, ws, out);
}